// Round 5
// baseline (1227.765 us; speedup 1.0000x reference)
//
#include <hip/hip_runtime.h>
#include <math.h>

// FNO3D: B=8, C=3, H=W=64, T=32, WIDTH=32, modes 8x8x8 (4 corners), 4 layers.
// Round 5: branch-free fast erf (A&S 7.1.26, |err|<=1.5e-7), scale constants
// folded into twiddles/staging, float4 spectral LDS reads, halved x live range.
//
// ws floats: X 33,554,432 | T1 16,777,216 | T2 4,194,304 | T3 1,048,576 | T4 1,048,576

#define TWO_PI 6.2831853071795864769f

// gelu(v) = 0.5 v (1 + erf(v/sqrt2)), erf via Abramowitz-Stegun 7.1.26 (branch-free).
__device__ __forceinline__ float gelu_fast(float v) {
    float u = v * 0.70710678118654752f;
    float a = fabsf(u);
    float t = __builtin_amdgcn_rcpf(fmaf(0.3275911f, a, 1.0f));
    float p = t * (0.254829592f + t * (-0.284496736f + t * (1.421413741f +
              t * (-1.453152027f + t * 1.061405429f))));
    float e = __expf(-u * u);
    float m = fmaf(-p, e, 1.0f);          // erf(|u|)
    float erfu = copysignf(m, u);
    return 0.5f * v * (1.0f + erfu);
}

// Goertzel constants for N=32, k=0..7
#define GOERTZEL_CONSTS \
    const float C2[8] = {2.0f, 1.9615705608f, 1.8477590650f, 1.6629392246f, \
                         1.4142135624f, 1.1111404660f, 0.7653668647f, 0.3901806440f}; \
    const float CK[8] = {1.0f, 0.9807852804f, 0.9238795325f, 0.8314696123f, \
                         0.7071067812f, 0.5555702330f, 0.3826834324f, 0.1950903220f}; \
    const float SK[8] = {0.0f, 0.1950903220f, 0.3826834324f, 0.5555702330f, \
                         0.7071067812f, 0.8314696123f, 0.9238795325f, 0.9807852804f};

// doubled twiddles e^{+j 2pi k t/32}: ck2[k]=2cos, sk2[k]=2sin, k=1..7
#define MAKE_TWIDDLES(t) \
    float ck2[8], sk2[8]; \
    float c1, s1v; sincosf((t) * (TWO_PI / 32.0f), &s1v, &c1); \
    ck2[1] = 2.0f * c1; sk2[1] = 2.0f * s1v; \
    _Pragma("unroll") \
    for (int k = 2; k < 8; ++k) { \
        float nc = ck2[k-1] * c1 - sk2[k-1] * s1v; \
        float ns = sk2[k-1] * c1 + ck2[k-1] * s1v; \
        ck2[k] = nc; sk2[k] = ns; \
    }

// spectral irfft-t term from scaled float4 tile row (15 FMA, 4 ds_read_b128)
__device__ __forceinline__ float spec_term(const float4* f4, const float* ck2, const float* sk2) {
    float4 q0 = f4[0], q1 = f4[1], q2 = f4[2], q3 = f4[3];
    float spr = q0.x;
    spr += q0.z * ck2[1] - q0.w * sk2[1];
    spr += q1.x * ck2[2] - q1.y * sk2[2];
    spr += q1.z * ck2[3] - q1.w * sk2[3];
    spr += q2.x * ck2[4] - q2.y * sk2[4];
    spr += q2.z * ck2[5] - q2.w * sk2[5];
    spr += q3.x * ck2[6] - q3.y * sk2[6];
    spr += q3.z * ck2[7] - q3.w * sk2[7];
    return spr;
}

// ---- lift: x_t + grid -> p conv -> X [b][sp][t][c]; fused Goertzel -> T1 ----
__global__ __launch_bounds__(256) void k_lift(const float* __restrict__ xt,
                                              const float* __restrict__ pw,
                                              const float* __restrict__ pb,
                                              float* __restrict__ X,
                                              float2* __restrict__ T1) {
    __shared__ float xs[8448];          // [spl8][t32] rows of 33 (pad)
    int g = blockIdx.x;                 // b*512 + spt ; 4096 blocks
    int spt = g & 511, b = g >> 9;
    int sp0 = spt * 8;
    int y = sp0 >> 6, x0 = sp0 & 63;
    int tid = threadIdx.x;
    int t = tid & 31, spl = tid >> 5;
    int sp = sp0 + spl;
    float a0 = xt[(b * 3 + 0) * 4096 + sp];
    float a1 = xt[(b * 3 + 1) * 4096 + sp];
    float a2 = xt[(b * 3 + 2) * 4096 + sp];
    float gy = y * (1.0f / 63.0f), gx = (x0 + spl) * (1.0f / 63.0f), gt = t * (1.0f / 31.0f);
    float v[32];
    #pragma unroll
    for (int c = 0; c < 32; ++c) {
        const float* w = pw + c * 6;
        v[c] = pb[c] + w[0] * a0 + w[1] * a1 + w[2] * a2
             + w[3] * gy + w[4] * gx + w[5] * gt;
    }
    float* xg = X + (((long)(b * 4096 + sp)) * 32 + t) * 32;
    #pragma unroll
    for (int j = 0; j < 8; ++j)
        ((float4*)xg)[j] = make_float4(v[4*j], v[4*j+1], v[4*j+2], v[4*j+3]);
    float* row = xs + (spl * 32 + t) * 33;
    #pragma unroll
    for (int c = 0; c < 32; ++c) row[c] = v[c];
    __syncthreads();
    int c = tid & 31, sl = tid >> 5;
    GOERTZEL_CONSTS
    float s1[8], s2[8];
    #pragma unroll
    for (int k = 0; k < 8; ++k) { s1[k] = 0.f; s2[k] = 0.f; }
    const float* col = xs + (sl * 32) * 33 + c;
    for (int tt = 0; tt < 32; ++tt) {
        float xv = col[tt * 33];
        #pragma unroll
        for (int k = 0; k < 8; ++k) {
            float s0 = xv + C2[k] * s1[k] - s2[k];
            s2[k] = s1[k]; s1[k] = s0;
        }
    }
    float2* ob = T1 + ((long)(b * 32 + c) * 4096 + sp0 + sl) * 8;
    #pragma unroll
    for (int k = 0; k < 8; ++k)
        ob[k] = make_float2(CK[k] * s1[k] - s2[k], SK[k] * s1[k]);
}

// ---------------- forward x-DFT: T1 -> T2 (16 modes) ----------------
__global__ __launch_bounds__(256) void k_xdft(const float2* __restrict__ T1, float2* __restrict__ T2) {
    __shared__ float2 s[1024];
    __shared__ float2 tw[64];
    int g = blockIdx.x;              // bc*32 + ypair ; 8192 blocks
    int ypair = g & 31; int bc = g >> 5;
    long base = ((long)bc * 64 + ypair * 2) * 512;
    int tid = threadIdx.x;
    for (int k = tid; k < 1024; k += 256) s[k] = T1[base + k];
    if (tid < 64) { float sn, cs; sincosf(tid * (TWO_PI / 64.0f), &sn, &cs); tw[tid] = make_float2(cs, sn); }
    __syncthreads();
    int half = tid >> 7, jj = tid & 127;
    int kxi = jj >> 3, kt = jj & 7;
    int kx = kxi < 8 ? kxi : kxi + 48;
    const float2* row = s + half * 512;
    float sr = 0.f, si = 0.f;
    for (int x = 0; x < 64; ++x) {
        float2 w = tw[(kx * x) & 63];
        float2 a = row[x * 8 + kt];
        sr += a.x * w.x + a.y * w.y;
        si += a.y * w.x - a.x * w.y;
    }
    T2[((long)bc * 64 + ypair * 2 + half) * 128 + jj] = make_float2(sr, si);
}

// ---------------- forward y-DFT: T2 -> T3 (16 modes) ----------------
__global__ __launch_bounds__(128) void k_ydft(const float2* __restrict__ T2, float2* __restrict__ T3) {
    __shared__ float2 s[512];
    __shared__ float2 tw[64];
    int g = blockIdx.x;              // bc*16 + kx ; 4096 blocks
    int kx = g & 15; int bc = g >> 4;
    int tid = threadIdx.x;
    for (int k = tid; k < 512; k += 128) {
        int y = k >> 3, kt = k & 7;
        s[k] = T2[((long)bc * 64 + y) * 128 + kx * 8 + kt];
    }
    if (tid < 64) { float sn, cs; sincosf(tid * (TWO_PI / 64.0f), &sn, &cs); tw[tid] = make_float2(cs, sn); }
    __syncthreads();
    int kyi = tid >> 3, kt = tid & 7;
    int ky = kyi < 8 ? kyi : kyi + 48;
    float sr = 0.f, si = 0.f;
    for (int y = 0; y < 64; ++y) {
        float2 w = tw[(ky * y) & 63];
        float2 a = s[y * 8 + kt];
        sr += a.x * w.x + a.y * w.y;
        si += a.y * w.x - a.x * w.y;
    }
    T3[((long)bc * 256 + kyi * 16 + kx) * 8 + kt] = make_float2(sr, si);
}

// -------- mode mix (mode-major, b-loop amortizes weight reads) --------
__global__ __launch_bounds__(256) void k_mix2(const float2* __restrict__ T3,
                                              const float* __restrict__ wr,
                                              const float* __restrict__ wi,
                                              float2* __restrict__ T4, int layer) {
    __shared__ float2 s[2304];       // [i=32][b=8] rows padded to 9 f2
    int mode = blockIdx.x;           // 256 blocks
    int kyi = mode >> 4, kxi = mode & 15;
    int tid = threadIdx.x;
    {
        int bb = tid >> 5, i = tid & 31;
        const float2* src = T3 + ((long)(bb * 32 + i) * 256 + mode) * 8;
        float2* dst = s + (i * 8 + bb) * 9;
        #pragma unroll
        for (int k = 0; k < 8; ++k) dst[k] = src[k];
    }
    __syncthreads();
    int corner = (kyi >= 8 ? 1 : 0) + (kxi >= 8 ? 2 : 0);
    long wbase = (long)(layer * 4 + corner) * 524288 + (long)(kyi & 7) * 64 + (long)(kxi & 7) * 8;
    int o = tid >> 3, kt = tid & 7;
    long wb = wbase + (long)o * 512 + kt;
    float2 acc[8];
    #pragma unroll
    for (int bb = 0; bb < 8; ++bb) acc[bb] = make_float2(0.f, 0.f);
    for (int i = 0; i < 32; ++i) {
        float r = wr[wb + (long)i * 16384], im = wi[wb + (long)i * 16384];
        #pragma unroll
        for (int bb = 0; bb < 8; ++bb) {
            float2 a = s[(i * 8 + bb) * 9 + kt];
            acc[bb].x += a.x * r - a.y * im;
            acc[bb].y += a.x * im + a.y * r;
        }
    }
    #pragma unroll
    for (int bb = 0; bb < 8; ++bb)
        T4[((long)(bb * 32 + o) * 256 + mode) * 8 + kt] = acc[bb];
}

// ---------------- inverse y: T4 -> T2 space ----------------
__global__ __launch_bounds__(256) void k_invy(const float2* __restrict__ T4, float2* __restrict__ T5) {
    __shared__ float2 s[128];
    __shared__ float2 tw[64];
    int g = blockIdx.x;              // bc*16 + kx ; 4096 blocks
    int kx = g & 15; int bc = g >> 4;
    int tid = threadIdx.x;
    if (tid < 128) {
        int kyi = tid >> 3, kt = tid & 7;
        s[tid] = T4[((long)bc * 256 + kyi * 16 + kx) * 8 + kt];
    } else if (tid < 192) {
        int m = tid - 128; float sn, cs; sincosf(m * (TWO_PI / 64.0f), &sn, &cs); tw[m] = make_float2(cs, sn);
    }
    __syncthreads();
    for (int r = 0; r < 2; ++r) {
        int j = tid + r * 256;
        int y = j >> 3, kt = j & 7;
        float sr = 0.f, si = 0.f;
        for (int kyi = 0; kyi < 16; ++kyi) {
            int ky = kyi < 8 ? kyi : kyi + 48;
            float2 w = tw[(ky * y) & 63];
            float2 a = s[kyi * 8 + kt];
            sr += a.x * w.x - a.y * w.y;
            si += a.y * w.x + a.x * w.y;
        }
        T5[((long)bc * 64 + y) * 128 + kx * 8 + kt] = make_float2(sr, si);
    }
}

// ---------------- inverse x: T2 space -> T1 space (T6) ----------------
__global__ __launch_bounds__(256) void k_invx(const float2* __restrict__ T5, float2* __restrict__ T6) {
    __shared__ float2 s[128];
    __shared__ float2 tw[64];
    int g = blockIdx.x;              // bc*64 + y ; 16384 blocks
    int tid = threadIdx.x;
    if (tid < 128) {
        s[tid] = T5[(long)g * 128 + tid];
    } else if (tid < 192) {
        int m = tid - 128; float sn, cs; sincosf(m * (TWO_PI / 64.0f), &sn, &cs); tw[m] = make_float2(cs, sn);
    }
    __syncthreads();
    for (int r = 0; r < 2; ++r) {
        int j = tid + r * 256;
        int x = j >> 3, kt = j & 7;
        float sr = 0.f, si = 0.f;
        for (int kxi = 0; kxi < 16; ++kxi) {
            int kx = kxi < 8 ? kxi : kxi + 48;
            float2 w = tw[(kx * x) & 63];
            float2 a = s[kxi * 8 + kt];
            sr += a.x * w.x - a.y * w.y;
            si += a.y * w.x + a.x * w.y;
        }
        T6[(long)g * 512 + j] = make_float2(sr, si);
    }
}

// ---- fuse2: pointwise (float4 X) + irfft-t + gelu, in-place X; Goertzel -> T1 ----
__global__ __launch_bounds__(256) void k_fuse2(float* __restrict__ X, const float2* __restrict__ T6,
                                               const float* __restrict__ pww,
                                               const float* __restrict__ pwb,
                                               float2* __restrict__ T1, int layer) {
    __shared__ float smem[8448];     // union: ts (2112 f2 = 16896B) / xs (8448 f)
    float2* ts = (float2*)smem;
    int g = blockIdx.x;              // b*512 + spt ; 4096 blocks
    int spt = g & 511, b = g >> 9;
    int sp0 = spt * 8;
    int tid = threadIdx.x;
    {   // stage spectral tile pre-scaled by 1/131072: ts[o][spl][kt], rows of 66 f2
        int o = tid >> 3, spl8 = tid & 7;
        const float4* src = (const float4*)(T6 + ((long)(b * 32 + o) * 4096 + sp0 + spl8) * 8);
        float4* dst = (float4*)(ts + o * 66 + spl8 * 8);
        const float S = 1.0f / 131072.0f;
        #pragma unroll
        for (int j = 0; j < 4; ++j) {
            float4 q = src[j];
            dst[j] = make_float4(q.x * S, q.y * S, q.z * S, q.w * S);
        }
    }
    __syncthreads();
    int t = tid & 31, spl = tid >> 5;
    int sp = sp0 + spl;
    MAKE_TWIDDLES(t)
    const float* wl = pww + layer * 1024;
    const float* bl = pwb + layer * 32;
    float* xg = X + (((long)(b * 4096 + sp)) * 32 + t) * 32;
    float acc[32];
    #pragma unroll
    for (int o = 0; o < 32; ++o) acc[o] = bl[o];
    {   // first input half
        float xh[16];
        #pragma unroll
        for (int j = 0; j < 4; ++j) {
            float4 q = ((const float4*)xg)[j];
            xh[4*j] = q.x; xh[4*j+1] = q.y; xh[4*j+2] = q.z; xh[4*j+3] = q.w;
        }
        #pragma unroll
        for (int i = 0; i < 16; ++i) {
            float xv = xh[i];
            #pragma unroll
            for (int o = 0; o < 32; ++o) acc[o] += wl[o * 32 + i] * xv;
        }
    }
    {   // second input half
        float xh[16];
        #pragma unroll
        for (int j = 0; j < 4; ++j) {
            float4 q = ((const float4*)xg)[4 + j];
            xh[4*j] = q.x; xh[4*j+1] = q.y; xh[4*j+2] = q.z; xh[4*j+3] = q.w;
        }
        #pragma unroll
        for (int i = 0; i < 16; ++i) {
            float xv = xh[i];
            #pragma unroll
            for (int o = 0; o < 32; ++o) acc[o] += wl[o * 32 + 16 + i] * xv;
        }
    }
    #pragma unroll
    for (int o = 0; o < 32; ++o) {
        const float4* f4 = (const float4*)(ts + o * 66 + spl * 8);
        acc[o] = gelu_fast(acc[o] + spec_term(f4, ck2, sk2));
    }
    #pragma unroll
    for (int j = 0; j < 8; ++j)
        ((float4*)xg)[j] = make_float4(acc[4*j], acc[4*j+1], acc[4*j+2], acc[4*j+3]);
    __syncthreads();                  // ts reads done; reuse smem as xs
    float* row = smem + (spl * 32 + t) * 33;
    #pragma unroll
    for (int c = 0; c < 32; ++c) row[c] = acc[c];
    __syncthreads();
    // Goertzel t-DFT for next layer
    int c = tid & 31, sl = tid >> 5;
    GOERTZEL_CONSTS
    float s1[8], s2[8];
    #pragma unroll
    for (int k = 0; k < 8; ++k) { s1[k] = 0.f; s2[k] = 0.f; }
    const float* col = smem + (sl * 32) * 33 + c;
    for (int tt = 0; tt < 32; ++tt) {
        float xv = col[tt * 33];
        #pragma unroll
        for (int k = 0; k < 8; ++k) {
            float s0 = xv + C2[k] * s1[k] - s2[k];
            s2[k] = s1[k]; s1[k] = s0;
        }
    }
    float2* ob = T1 + ((long)(b * 32 + c) * 4096 + sp0 + sl) * 8;
    #pragma unroll
    for (int k = 0; k < 8; ++k)
        ob[k] = make_float2(CK[k] * s1[k] - s2[k], SK[k] * s1[k]);
}

// ---- fuse2_last: layer 3 + head (q1,gelu,q2) -> out ----
__global__ __launch_bounds__(256) void k_fuse2_last(const float* __restrict__ X, const float2* __restrict__ T6,
                                                    const float* __restrict__ pww, const float* __restrict__ pwb,
                                                    const float* __restrict__ q1w, const float* __restrict__ q1b,
                                                    const float* __restrict__ q2w, const float* __restrict__ q2b,
                                                    float* __restrict__ out) {
    __shared__ float smem[4224];     // ts 2112 f2 / st 864 f
    float2* ts = (float2*)smem;
    int g = blockIdx.x;              // b*512 + spt ; 4096 blocks
    int spt = g & 511, b = g >> 9;
    int sp0 = spt * 8;
    int tid = threadIdx.x;
    {
        int o = tid >> 3, spl8 = tid & 7;
        const float4* src = (const float4*)(T6 + ((long)(b * 32 + o) * 4096 + sp0 + spl8) * 8);
        float4* dst = (float4*)(ts + o * 66 + spl8 * 8);
        const float S = 1.0f / 131072.0f;
        #pragma unroll
        for (int j = 0; j < 4; ++j) {
            float4 q = src[j];
            dst[j] = make_float4(q.x * S, q.y * S, q.z * S, q.w * S);
        }
    }
    __syncthreads();
    int t = tid & 31, spl = tid >> 5;
    int sp = sp0 + spl;
    MAKE_TWIDDLES(t)
    const float* wl = pww + 3 * 1024;
    const float* bl = pwb + 3 * 32;
    const float* xg = X + (((long)(b * 4096 + sp)) * 32 + t) * 32;
    float acc[32];
    #pragma unroll
    for (int o = 0; o < 32; ++o) acc[o] = bl[o];
    {
        float xh[16];
        #pragma unroll
        for (int j = 0; j < 4; ++j) {
            float4 q = ((const float4*)xg)[j];
            xh[4*j] = q.x; xh[4*j+1] = q.y; xh[4*j+2] = q.z; xh[4*j+3] = q.w;
        }
        #pragma unroll
        for (int i = 0; i < 16; ++i) {
            float xv = xh[i];
            #pragma unroll
            for (int o = 0; o < 32; ++o) acc[o] += wl[o * 32 + i] * xv;
        }
    }
    {
        float xh[16];
        #pragma unroll
        for (int j = 0; j < 4; ++j) {
            float4 q = ((const float4*)xg)[4 + j];
            xh[4*j] = q.x; xh[4*j+1] = q.y; xh[4*j+2] = q.z; xh[4*j+3] = q.w;
        }
        #pragma unroll
        for (int i = 0; i < 16; ++i) {
            float xv = xh[i];
            #pragma unroll
            for (int o = 0; o < 32; ++o) acc[o] += wl[o * 32 + 16 + i] * xv;
        }
    }
    #pragma unroll
    for (int o = 0; o < 32; ++o) {
        const float4* f4 = (const float4*)(ts + o * 66 + spl * 8);
        acc[o] = gelu_fast(acc[o] + spec_term(f4, ck2, sk2));
    }
    // head
    float o0 = q2b[0], o1 = q2b[1], o2 = q2b[2];
    #pragma unroll
    for (int j = 0; j < 64; ++j) {
        float h = q1b[j];
        #pragma unroll
        for (int i = 0; i < 32; ++i) h += q1w[j * 32 + i] * acc[i];
        h = gelu_fast(h);
        o0 += q2w[j] * h;
        o1 += q2w[64 + j] * h;
        o2 += q2w[128 + j] * h;
    }
    __syncthreads();
    float* st = smem;                // [t][c] rows of 9 (pad): conflict-free
    st[(t * 3 + 0) * 9 + spl] = o0;
    st[(t * 3 + 1) * 9 + spl] = o1;
    st[(t * 3 + 2) * 9 + spl] = o2;
    __syncthreads();
    int t2 = tid >> 3, spl2 = tid & 7;
    #pragma unroll
    for (int c = 0; c < 3; ++c)
        out[((long)(b * 32 + t2) * 3 + c) * 4096 + sp0 + spl2] = st[(t2 * 3 + c) * 9 + spl2];
}

extern "C" void kernel_launch(void* const* d_in, const int* in_sizes, int n_in,
                              void* d_out, int out_size, void* d_ws, size_t ws_size,
                              hipStream_t stream) {
    const float* xt  = (const float*)d_in[0];
    const float* pw  = (const float*)d_in[1];
    const float* pb  = (const float*)d_in[2];
    const float* swr = (const float*)d_in[3];
    const float* swi = (const float*)d_in[4];
    const float* pww = (const float*)d_in[5];
    const float* pwb = (const float*)d_in[6];
    const float* q1w = (const float*)d_in[7];
    const float* q1b = (const float*)d_in[8];
    const float* q2w = (const float*)d_in[9];
    const float* q2b = (const float*)d_in[10];
    float* out = (float*)d_out;

    float*  X  = (float*)d_ws;
    float2* T1 = (float2*)(X + 33554432);
    float2* T2 = (float2*)((float*)T1 + 16777216);
    float2* T3 = (float2*)((float*)T2 + 4194304);
    float2* T4 = (float2*)((float*)T3 + 1048576);

    k_lift<<<4096, 256, 0, stream>>>(xt, pw, pb, X, T1);
    for (int l = 0; l < 4; ++l) {
        k_xdft<<<8192, 256, 0, stream>>>(T1, T2);
        k_ydft<<<4096, 128, 0, stream>>>(T2, T3);
        k_mix2<<<256, 256, 0, stream>>>(T3, swr, swi, T4, l);
        k_invy<<<4096, 256, 0, stream>>>(T4, T2);
        k_invx<<<16384, 256, 0, stream>>>(T2, T1);
        if (l < 3)
            k_fuse2<<<4096, 256, 0, stream>>>(X, T1, pww, pwb, T1, l);
        else
            k_fuse2_last<<<4096, 256, 0, stream>>>(X, T1, pww, pwb, q1w, q1b, q2w, q2b, out);
    }
}